// Round 9
// baseline (112.256 us; speedup 1.0000x reference)
//
#include <hip/hip_runtime.h>
#include <cstddef>
#include <math.h>

#define NEXP    45
#define DIM     256
#define NTOK    4096
#define KQ      16     // k's per block (lane&15)
#define TPW     12     // tokens per wave per pass (3 per lane-quarter)
#define PASS    96     // 8 waves * 12 tokens
#define LISTCAP 192    // m ~ 91 +- 9.4; 192 is >10 sigma
#define WROW    72     // padded quad stride (64 + 8): pad-shift swizzle

// Zero d_out (harness re-poisons to 0xAA before every timed launch).
__global__ void pos_zero_kernel(float* out) { out[threadIdx.x] = 0.0f; }

// R9 structure (post-mortems R4: s_load starve, R5: forced-VGPR spill, R8:
// out-of-order SMEM poisons lgkmcnt -> per-iteration drain, 20% VALUBusy).
// Clean pipe assignment: W per-lane from LDS (ds_read_b128, lgkmcnt has ONLY
// in-order LDS ops), x per-lane from global (global_load_dwordx4, vmcnt is a
// separate in-order counter the compiler pipelines with counted waits).
// Nothing streams through SGPRs. lane = (k in 16, token-quarter in 4); each
// lane: 3 tokens x 16 k... acc[3]; wave = 12 tokens x 16 k; block = expert x
// 16-k slice; grid 45x16=720 (2.8 blocks/CU). W tile [16][256] in LDS with
// pad-shift swizzle: row r quad dq at granule r*WROW+(r&7)+dq — ADD-based so
// dq folds into the ds immediate AND rows spread across all 8 bank-groups.
__global__ __launch_bounds__(512, 4)
void pos_expert_kernel(const float* __restrict__ x, const int* __restrict__ tags,
                       const float* __restrict__ W, const float* __restrict__ bias,
                       float* __restrict__ out) {
  __shared__ alignas(16) float WT[KQ * WROW * 4];  // 18 KB
  __shared__ int   list[LISTCAP];
  __shared__ float wmax[8][KQ];
  __shared__ int   cnt;

  const int tid  = threadIdx.x;
  const int lane = tid & 63;
  const int wv   = tid >> 6;
  const int qtr  = lane >> 4;        // token-quarter 0..3
  const int kl   = lane & 15;        // k within block

  // XCD-aware remap: 720 = 8*90; blocks of one expert (16 consecutive idx)
  // land on one XCD -> its L2 re-serves the expert's x rows across k-slices.
  const int idx720 = (blockIdx.x & 7) * 90 + (blockIdx.x >> 3);
  const int e  = idx720 >> 4;
  const int kq = (idx720 & 15) << 4;

  if (tid == 0) cnt = 0;
  __syncthreads();

  // ---- compact this expert's token indices (order irrelevant under max;
  // index masked so even impossible overflow stays in-bounds)
  for (int n = tid; n < NTOK; n += 512)
    if (tags[n] == e) list[atomicAdd(&cnt, 1) % LISTCAP] = n;

  // ---- stage W tile [16 rows x 64 quads]: 1024 quads, 512 threads x 2.
  // Consecutive tid = consecutive dq -> coalesced global; LDS writes land on
  // consecutive granules (conflict-free floor).
  {
    const float4* Wg = (const float4*)(W + ((size_t)e * DIM + kq) * DIM);
#pragma unroll
    for (int i = 0; i < 2; ++i) {
      const int q = tid + 512 * i;
      const int r = q >> 6, dq = q & 63;
      ((float4*)WT)[r * WROW + (r & 7) + dq] = Wg[(r << 6) + dq];
    }
  }
  __syncthreads();

  const int    m    = cnt;
  const float  bk   = bias[(size_t)e * DIM + kq + kl];
  const float4* xq   = (const float4*)x;
  const float4* wrow = (const float4*)WT + kl * WROW + (kl & 7);

  float mx = -INFINITY;

  for (int base = wv * TPW; base < m; base += PASS) {
    int  off[3];
    bool val[3];
#pragma unroll
    for (int j = 0; j < 3; ++j) {
      int t = base + qtr * 3 + j;
      val[j] = t < m;
      if (t >= m) t = m - 1;           // clamp: duplicate token, masked below
      off[j] = list[t] << 6;           // float4 index of token row
    }
    float acc[3] = {0.f, 0.f, 0.f};

    // Per dq window: 1 ds_read_b128 (W, imm offset off VGPR base) +
    // 3 global_load_dwordx4 (x, vmcnt, imm offsets) + 12 v_fmac (24 cyc).
#pragma unroll 4
    for (int dq = 0; dq < 64; ++dq) {
      const float4 w4 = wrow[dq];
#pragma unroll
      for (int j = 0; j < 3; ++j) {
        const float4 xv = xq[off[j] + dq];
        acc[j] += w4.x * xv.x + w4.y * xv.y + w4.z * xv.z + w4.w * xv.w;
      }
    }
#pragma unroll
    for (int j = 0; j < 3; ++j)
      if (val[j]) mx = fmaxf(mx, acc[j]);
  }

  // reduce across the 4 token-quarters (same kl at lane^16, lane^32)
  mx = fmaxf(mx, __shfl_xor(mx, 16, 64));
  mx = fmaxf(mx, __shfl_xor(mx, 32, 64));
  const float y = fmaxf(mx + bk, 0.0f);   // bias commutes past max; relu last
  if (qtr == 0) wmax[wv][kl] = y;         // m==0: y = relu(-inf+b) = 0 (no-op)
  __syncthreads();

  if (tid < KQ) {
    float v = wmax[0][tid];
#pragma unroll
    for (int w = 1; w < 8; ++w) v = fmaxf(v, wmax[w][tid]);
    // all values >= 0: int-bit compare is monotone; out zeroed by pos_zero_kernel
    atomicMax((int*)out + kq + tid, __float_as_int(v));
  }
}

extern "C" void kernel_launch(void* const* d_in, const int* in_sizes, int n_in,
                              void* d_out, int out_size, void* d_ws, size_t ws_size,
                              hipStream_t stream) {
  const float* x    = (const float*)d_in[0];
  const int*   tags = (const int*)d_in[1];
  const float* W    = (const float*)d_in[2];
  const float* b    = (const float*)d_in[3];
  float*       out  = (float*)d_out;

  pos_zero_kernel<<<1, 256, 0, stream>>>(out);
  pos_expert_kernel<<<NEXP * 16, 512, 0, stream>>>(x, tags, W, b, out);
}